// Round 3
// baseline (517.898 us; speedup 1.0000x reference)
//
#include <hip/hip_runtime.h>

#define VQ_N 131072   // rows = 32*64*64
#define VQ_D 64
#define VQ_K 512

// ws float layout:
//   [64 .. 64+512)        half codebook norms  0.5*||e_k||^2
//   [576 .. 576+32768)    transposed codebook cbt[K][D]
// loss accumulator lives in d_out[VQ_N*VQ_D] (zeroed by prep each launch).

__global__ __launch_bounds__(512) void vq_prep(const float* __restrict__ enc,
                                               float* __restrict__ ws,
                                               float* loss_acc) {
    int k = threadIdx.x;          // 0..511
    if (k == 0) loss_acc[0] = 0.0f;
    float* cbt = ws + 576;
    float hn = 0.0f;
    #pragma unroll 8
    for (int d = 0; d < VQ_D; ++d) {
        float v = enc[d * VQ_K + k];   // enc is [D][K] row-major
        cbt[k * VQ_D + d] = v;
        hn = fmaf(v, v, hn);
    }
    ws[64 + k] = 0.5f * hn;
}

// Exact-enough squared distance in fp64 (fp32*fp32 products are exact in f64).
__device__ double dist_f64(const float* __restrict__ xv, const float* __restrict__ e) {
    double acc = 0.0;
    #pragma unroll
    for (int d = 0; d < VQ_D; ++d) {
        double diff = (double)xv[d] - (double)e[d];
        acc = fma(diff, diff, acc);
    }
    return acc;
}

// Block: 256 threads = 4 waves; 128 rows/block, K split in half across t>>7.
// Grid 1024 blocks -> 4096 waves -> 4 waves/SIMD (launch_bounds caps VGPR<=128).
__global__ __launch_bounds__(256, 4) void vq_main(const float* __restrict__ x,
                                                  const float* __restrict__ ws,
                                                  float* __restrict__ out,
                                                  float* loss_acc) {
    const float* __restrict__ hnorm = ws + 64;
    const float* __restrict__ cbt   = ws + 576;

    const int t     = threadIdx.x;
    const int row   = blockIdx.x * 128 + (t & 127);
    const int kbase = (t >> 7) * 256;          // 0 or 256

    // Load this thread's row of x into registers (16 x float4).
    float xv[VQ_D];
    const float4* xr = reinterpret_cast<const float4*>(x + (size_t)row * VQ_D);
    #pragma unroll
    for (int j = 0; j < VQ_D / 4; ++j) {
        float4 v = xr[j];
        xv[4*j+0] = v.x; xv[4*j+1] = v.y; xv[4*j+2] = v.z; xv[4*j+3] = v.w;
    }

    // fp32 screening over this thread's K-half: track top-2 (strict < = first-occurrence).
    float best1 = 3.4e38f, best2 = 3.4e38f;
    int   i1 = 0,          i2 = 0;
    for (int kk = 0; kk < 256; ++kk) {
        const int k = kbase + kk;
        const float4* e = reinterpret_cast<const float4*>(cbt + k * VQ_D);
        float a0 = 0.f, a1 = 0.f, a2 = 0.f, a3 = 0.f;
        #pragma unroll
        for (int j = 0; j < VQ_D / 4; ++j) {
            float4 v = e[j];
            a0 = fmaf(xv[4*j+0], v.x, a0);
            a1 = fmaf(xv[4*j+1], v.y, a1);
            a2 = fmaf(xv[4*j+2], v.z, a2);
            a3 = fmaf(xv[4*j+3], v.w, a3);
        }
        // s_k = 0.5*||e_k||^2 - x.e_k  (same argmin as full squared distance)
        float s = hnorm[k] - ((a0 + a1) + (a2 + a3));
        if (s < best1) { best2 = best1; i2 = i1; best1 = s; i1 = k; }
        else if (s < best2) { best2 = s; i2 = k; }
    }

    // Publish per-half top-2, then threads 0..127 merge the two halves.
    __shared__ float4 mg[256];
    mg[t] = make_float4(best1, __int_as_float(i1), best2, __int_as_float(i2));
    __syncthreads();

    float lsum = 0.0f;
    if (t < 128) {
        float4 A = mg[t];            // half 0 (lower k indices)
        float4 B = mg[t + 128];      // half 1 (higher k indices)
        float a1s = A.x, a2s = A.z, b1s = B.x, b2s = B.z;
        int   a1i = __float_as_int(A.y), a2i = __float_as_int(A.w);
        int   b1i = __float_as_int(B.y), b2i = __float_as_int(B.w);
        // Merge two sorted pairs -> overall top-2; ties prefer half 0 (lower index).
        float f1s, f2s; int f1i, f2i;
        if (b1s < a1s) {
            f1s = b1s; f1i = b1i;
            if (a1s <= b2s) { f2s = a1s; f2i = a1i; } else { f2s = b2s; f2i = b2i; }
        } else {
            f1s = a1s; f1i = a1i;
            if (a2s <= b1s) { f2s = a2s; f2i = a2i; } else { f2s = b1s; f2i = b1i; }
        }
        (void)f1s; (void)f2s;

        // fp64 rescreen of the two finalists (matches float64 numpy argmin).
        double d1 = dist_f64(xv, cbt + f1i * VQ_D);
        double d2 = dist_f64(xv, cbt + f2i * VQ_D);
        int bidx;
        if (d1 < d2)      bidx = f1i;
        else if (d2 < d1) bidx = f2i;
        else              bidx = (f1i < f2i) ? f1i : f2i;

        // Gather winning codeword, write output, accumulate loss.
        const float4* q4 = reinterpret_cast<const float4*>(cbt + bidx * VQ_D);
        float4* o4 = reinterpret_cast<float4*>(out + (size_t)row * VQ_D);
        #pragma unroll
        for (int j = 0; j < VQ_D / 4; ++j) {
            float4 v = q4[j];
            o4[j] = v;
            float d0 = v.x - xv[4*j+0];
            float e1 = v.y - xv[4*j+1];
            float e2 = v.z - xv[4*j+2];
            float e3 = v.w - xv[4*j+3];
            lsum = fmaf(d0, d0, lsum);
            lsum = fmaf(e1, e1, lsum);
            lsum = fmaf(e2, e2, lsum);
            lsum = fmaf(e3, e3, lsum);
        }
    }
    // Threads 0..127 form waves 0 and 1 entirely -> full-wave shuffle reduce.
    #pragma unroll
    for (int off = 32; off > 0; off >>= 1)
        lsum += __shfl_xor(lsum, off, 64);
    if (t < 128 && (t & 63) == 0)
        atomicAdd(loss_acc, lsum);
}

__global__ void vq_finalize(float* loss_acc) {
    // loss = (BETA + 1) * mean((q-x)^2), BETA = 0.25
    loss_acc[0] = 1.25f * loss_acc[0] / (float)(VQ_N * VQ_D);
}

extern "C" void kernel_launch(void* const* d_in, const int* in_sizes, int n_in,
                              void* d_out, int out_size, void* d_ws, size_t ws_size,
                              hipStream_t stream) {
    const float* x   = (const float*)d_in[0];   // (32,64,64,64) fp32
    const float* enc = (const float*)d_in[1];   // (64,512) fp32
    float* out = (float*)d_out;                 // 8388608 quantised + 1 loss
    float* ws  = (float*)d_ws;
    float* loss_acc = out + (size_t)VQ_N * VQ_D;

    vq_prep<<<1, 512, 0, stream>>>(enc, ws, loss_acc);
    vq_main<<<VQ_N / 128, 256, 0, stream>>>(x, ws, out, loss_acc);
    vq_finalize<<<1, 1, 0, stream>>>(loss_acc);
}

// Round 4
// 75.530 us; speedup vs baseline: 6.8569x; 6.8569x over previous
//
#include <hip/hip_runtime.h>
#include <stdint.h>

#define VQ_N   131072   // rows = 32*64*64
#define VQ_D   64
#define VQ_K   512
#define NKT    32       // 512/16 k-tiles
#define NBLK   2048     // main-kernel blocks (4 waves each, 16 rows/wave)

typedef __attribute__((ext_vector_type(8))) short  short8;   // 8 x bf16 bits
typedef __attribute__((ext_vector_type(4))) float  f32x4;

// ws float-offsets:
#define WS_HN    0        // 512 f:  32 + 0.5*||e_k||^2
#define WS_CBT   512      // 512*64 f: codebook, codeword-major cbt[k][d]
#define WS_FRAG  33280    // 32768 f = bf16x8 frag[32 kt][4 j][64 lane]; j: 0=eh d0,1=eh d1,2=el d0,3=el d1
#define WS_PART  66048    // 2048 f: per-block loss partials

__device__ __forceinline__ unsigned short f2bf(float f) {   // RNE f32->bf16 bits
    unsigned u = __float_as_uint(f);
    u += 0x7FFFu + ((u >> 16) & 1u);
    return (unsigned short)(u >> 16);
}
__device__ __forceinline__ float bf2f(unsigned short h) {
    return __uint_as_float(((unsigned)h) << 16);
}

// Build negated bf16 split of 8 floats: yh = bf16(-x), yl = bf16(-x - yh)
__device__ __forceinline__ void cvt8neg(float4 a, float4 b, short8& hi, short8& lo) {
    float f[8] = {a.x, a.y, a.z, a.w, b.x, b.y, b.z, b.w};
    union { short8 v; unsigned short u[8]; } H, L;
    #pragma unroll
    for (int e = 0; e < 8; ++e) {
        float y = -f[e];
        unsigned short h = f2bf(y);
        H.u[e] = h;
        L.u[e] = f2bf(y - bf2f(h));
    }
    hi = H.v; lo = L.v;
}

__device__ __forceinline__ bool lexlt(float s1, unsigned i1, float s2, unsigned i2) {
    return (s1 < s2) || ((s1 == s2) && (i1 < i2));
}

// ---------------- prep: codebook norms, fp32 transpose, bf16-split B fragments ----
__global__ __launch_bounds__(64) void vq_prep(const float* __restrict__ enc,
                                              float* __restrict__ ws) {
    const int k  = blockIdx.x * 64 + threadIdx.x;   // 0..511
    const int kt = k >> 4, c = k & 15;
    float* cbt = ws + WS_CBT;
    unsigned short* frag = (unsigned short*)(ws + WS_FRAG);
    double hs = 0.0;
    for (int d = 0; d < VQ_D; ++d) {
        float v = enc[d * VQ_K + k];               // enc is [D][K]
        cbt[k * VQ_D + d] = v;
        hs += (double)v * (double)v;
        const int t = d >> 5, g = (d >> 3) & 3, e = d & 7;
        const int lane = 16 * g + c;
        unsigned short h = f2bf(v);
        frag[(((kt * 4) + t)     * 64 + lane) * 8 + e] = h;              // eh
        frag[(((kt * 4) + 2 + t) * 64 + lane) * 8 + e] = f2bf(v - bf2f(h)); // el
    }
    ws[WS_HN + k] = 32.0f + 0.5f * (float)hs;      // +32 keeps screen scores positive
}

// ---------------- main: MFMA screen + top-2 + f64 rescreen + write + loss --------
__global__ __launch_bounds__(256) void vq_main(const float* __restrict__ x,
                                               const float* __restrict__ ws,
                                               float* __restrict__ out,
                                               float* __restrict__ partials) {
    const int tid = threadIdx.x;
    const int l   = tid & 63;          // lane
    const int wid = tid >> 6;          // wave in block
    const int m   = l & 15;            // A-row / C-col within tile
    const int g   = l >> 4;            // k-group
    const int row = (blockIdx.x * 4 + wid) * 16 + m;

    const float*  __restrict__ hn   = ws + WS_HN;
    const float*  __restrict__ cbt  = ws + WS_CBT;
    const short8* __restrict__ frag = (const short8*)(ws + WS_FRAG);

    // x-row fragment: lane holds row m, d in [8g,8g+8) and [32+8g,32+8g+8)
    const float* xr = x + (size_t)row * VQ_D;
    float4 xa0 = *(const float4*)(xr + 8 * g);
    float4 xa1 = *(const float4*)(xr + 8 * g + 4);
    float4 xb0 = *(const float4*)(xr + 32 + 8 * g);
    float4 xb1 = *(const float4*)(xr + 32 + 8 * g + 4);

    short8 yh0, yl0, yh1, yl1;                  // negated bf16 split of x
    cvt8neg(xa0, xa1, yh0, yl0);
    cvt8neg(xb0, xb1, yh1, yl1);

    // per-lane top-2 over scores s = 32 + 0.5||e||^2 - x.e  (C rows 4g+r, col-k = 16kt+m)
    float    b1s[4], b2s[4];
    unsigned b1i[4], b2i[4];
    #pragma unroll
    for (int r = 0; r < 4; ++r) { b1s[r] = b2s[r] = 3.4e38f; b1i[r] = b2i[r] = 0; }

    for (int kt = 0; kt < NKT; ++kt) {
        short8 f0 = frag[(kt * 4 + 0) * 64 + l];   // eh dtile0
        short8 f1 = frag[(kt * 4 + 1) * 64 + l];   // eh dtile1
        short8 f2 = frag[(kt * 4 + 2) * 64 + l];   // el dtile0
        short8 f3 = frag[(kt * 4 + 3) * 64 + l];   // el dtile1
        float h = hn[kt * 16 + m];
        f32x4 a = {h, h, h, h};
        f32x4 b = {0.f, 0.f, 0.f, 0.f};
        a = __builtin_amdgcn_mfma_f32_16x16x32_bf16(yh0, f0, a, 0, 0, 0);
        b = __builtin_amdgcn_mfma_f32_16x16x32_bf16(yh1, f1, b, 0, 0, 0);
        a = __builtin_amdgcn_mfma_f32_16x16x32_bf16(yl0, f0, a, 0, 0, 0);
        b = __builtin_amdgcn_mfma_f32_16x16x32_bf16(yl1, f1, b, 0, 0, 0);
        a = __builtin_amdgcn_mfma_f32_16x16x32_bf16(yh0, f2, a, 0, 0, 0);
        b = __builtin_amdgcn_mfma_f32_16x16x32_bf16(yh1, f3, b, 0, 0, 0);
        const unsigned kb = (unsigned)(kt * 16 + m);
        #pragma unroll
        for (int r = 0; r < 4; ++r) {
            float s = a[r] + b[r];
            bool c1 = s < b1s[r];
            bool c2 = s < b2s[r];
            float    ns2 = c1 ? b1s[r] : s;
            unsigned ni2 = c1 ? b1i[r] : kb;
            b2s[r] = c2 ? ns2 : b2s[r];
            b2i[r] = c2 ? ni2 : b2i[r];
            b1s[r] = c1 ? s  : b1s[r];
            b1i[r] = c1 ? kb : b1i[r];
        }
    }

    // butterfly top-2 merge within each 16-lane group (rows 4g+r live in group g)
    #pragma unroll
    for (int st = 1; st <= 8; st <<= 1) {
        #pragma unroll
        for (int r = 0; r < 4; ++r) {
            float    o1s = __shfl_xor(b1s[r], st, 64);
            unsigned o1i = (unsigned)__shfl_xor((int)b1i[r], st, 64);
            float    o2s = __shfl_xor(b2s[r], st, 64);
            unsigned o2i = (unsigned)__shfl_xor((int)b2i[r], st, 64);
            bool c = lexlt(o1s, o1i, b1s[r], b1i[r]);
            float    n1s = c ? o1s : b1s[r];
            unsigned n1i = c ? o1i : b1i[r];
            float    lss = c ? b1s[r] : o1s;     // loser of the firsts
            unsigned lsi = c ? b1i[r] : o1i;
            bool c2 = lexlt(b2s[r], b2i[r], o2s, o2i);
            float    m2s = c2 ? b2s[r] : o2s;
            unsigned m2i = c2 ? b2i[r] : o2i;
            bool c3 = lexlt(lss, lsi, m2s, m2i);
            b1s[r] = n1s; b1i[r] = n1i;
            b2s[r] = c3 ? lss : m2s;
            b2i[r] = c3 ? lsi : m2i;
        }
    }

    // redistribute: lane l (owns row m=l&15) fetches its row's finalists from group m>>2
    const int srcLane = (m >> 2) * 16;
    unsigned i1 = 0, i2 = 0;
    #pragma unroll
    for (int r = 0; r < 4; ++r) {
        unsigned v1 = (unsigned)__shfl((int)b1i[r], srcLane, 64);
        unsigned v2 = (unsigned)__shfl((int)b2i[r], srcLane, 64);
        if ((m & 3) == r) { i1 = v1; i2 = v2; }
    }

    // fp64 rescreen of the two finalists over this lane's 16 d's, team-reduced (4 lanes/row)
    const float* e1p = cbt + (size_t)i1 * VQ_D;
    const float* e2p = cbt + (size_t)i2 * VQ_D;
    float4 p10 = *(const float4*)(e1p + 8 * g);
    float4 p11 = *(const float4*)(e1p + 8 * g + 4);
    float4 p12 = *(const float4*)(e1p + 32 + 8 * g);
    float4 p13 = *(const float4*)(e1p + 32 + 8 * g + 4);
    float4 p20 = *(const float4*)(e2p + 8 * g);
    float4 p21 = *(const float4*)(e2p + 8 * g + 4);
    float4 p22 = *(const float4*)(e2p + 32 + 8 * g);
    float4 p23 = *(const float4*)(e2p + 32 + 8 * g + 4);

    double dd1 = 0.0, dd2 = 0.0;
    {
        const float xs[16] = {xa0.x,xa0.y,xa0.z,xa0.w, xa1.x,xa1.y,xa1.z,xa1.w,
                              xb0.x,xb0.y,xb0.z,xb0.w, xb1.x,xb1.y,xb1.z,xb1.w};
        const float q1[16] = {p10.x,p10.y,p10.z,p10.w, p11.x,p11.y,p11.z,p11.w,
                              p12.x,p12.y,p12.z,p12.w, p13.x,p13.y,p13.z,p13.w};
        const float q2[16] = {p20.x,p20.y,p20.z,p20.w, p21.x,p21.y,p21.z,p21.w,
                              p22.x,p22.y,p22.z,p22.w, p23.x,p23.y,p23.z,p23.w};
        #pragma unroll
        for (int j = 0; j < 16; ++j) {
            double u1 = (double)xs[j] - (double)q1[j];
            double u2 = (double)xs[j] - (double)q2[j];
            dd1 = fma(u1, u1, dd1);
            dd2 = fma(u2, u2, dd2);
        }
    }
    dd1 += __shfl_xor(dd1, 16, 64);  dd1 += __shfl_xor(dd1, 32, 64);
    dd2 += __shfl_xor(dd2, 16, 64);  dd2 += __shfl_xor(dd2, 32, 64);
    const bool take1 = (dd1 < dd2) || ((dd1 == dd2) && (i1 < i2));  // np first-occurrence

    // select winner codeword values, write output, accumulate loss
    float4 q0, q1v, q2v, q3v;
    q0.x = take1 ? p10.x : p20.x; q0.y = take1 ? p10.y : p20.y; q0.z = take1 ? p10.z : p20.z; q0.w = take1 ? p10.w : p20.w;
    q1v.x = take1 ? p11.x : p21.x; q1v.y = take1 ? p11.y : p21.y; q1v.z = take1 ? p11.z : p21.z; q1v.w = take1 ? p11.w : p21.w;
    q2v.x = take1 ? p12.x : p22.x; q2v.y = take1 ? p12.y : p22.y; q2v.z = take1 ? p12.z : p22.z; q2v.w = take1 ? p12.w : p22.w;
    q3v.x = take1 ? p13.x : p23.x; q3v.y = take1 ? p13.y : p23.y; q3v.z = take1 ? p13.z : p23.z; q3v.w = take1 ? p13.w : p23.w;

    float* orow = out + (size_t)row * VQ_D;
    *(float4*)(orow + 8 * g)          = q0;
    *(float4*)(orow + 8 * g + 4)      = q1v;
    *(float4*)(orow + 32 + 8 * g)     = q2v;
    *(float4*)(orow + 32 + 8 * g + 4) = q3v;

    float ls = 0.f;
    {
        float d;
        d = q0.x - xa0.x; ls = fmaf(d, d, ls);  d = q0.y - xa0.y; ls = fmaf(d, d, ls);
        d = q0.z - xa0.z; ls = fmaf(d, d, ls);  d = q0.w - xa0.w; ls = fmaf(d, d, ls);
        d = q1v.x - xa1.x; ls = fmaf(d, d, ls); d = q1v.y - xa1.y; ls = fmaf(d, d, ls);
        d = q1v.z - xa1.z; ls = fmaf(d, d, ls); d = q1v.w - xa1.w; ls = fmaf(d, d, ls);
        d = q2v.x - xb0.x; ls = fmaf(d, d, ls); d = q2v.y - xb0.y; ls = fmaf(d, d, ls);
        d = q2v.z - xb0.z; ls = fmaf(d, d, ls); d = q2v.w - xb0.w; ls = fmaf(d, d, ls);
        d = q3v.x - xb1.x; ls = fmaf(d, d, ls); d = q3v.y - xb1.y; ls = fmaf(d, d, ls);
        d = q3v.z - xb1.z; ls = fmaf(d, d, ls); d = q3v.w - xb1.w; ls = fmaf(d, d, ls);
    }
    #pragma unroll
    for (int off = 32; off > 0; off >>= 1) ls += __shfl_xor(ls, off, 64);

    __shared__ float lsw[4];
    if ((tid & 63) == 0) lsw[wid] = ls;
    __syncthreads();
    if (tid == 0) partials[blockIdx.x] = lsw[0] + lsw[1] + lsw[2] + lsw[3];
}

// ---------------- finalize: deterministic partial-sum + scale ---------------------
__global__ __launch_bounds__(256) void vq_fin(const float* __restrict__ partials,
                                              float* __restrict__ out) {
    const int tid = threadIdx.x;
    float s = 0.f;
    #pragma unroll
    for (int j = 0; j < NBLK / 256; ++j) s += partials[tid + 256 * j];
    #pragma unroll
    for (int off = 32; off > 0; off >>= 1) s += __shfl_xor(s, off, 64);
    __shared__ float w[4];
    if ((tid & 63) == 0) w[tid >> 6] = s;
    __syncthreads();
    if (tid == 0)
        out[(size_t)VQ_N * VQ_D] = 1.25f * (w[0] + w[1] + w[2] + w[3]) / 8388608.0f;
}

extern "C" void kernel_launch(void* const* d_in, const int* in_sizes, int n_in,
                              void* d_out, int out_size, void* d_ws, size_t ws_size,
                              hipStream_t stream) {
    const float* x   = (const float*)d_in[0];   // (32,64,64,64) fp32
    const float* enc = (const float*)d_in[1];   // (64,512) fp32
    float* out = (float*)d_out;                 // 8388608 quantised + 1 loss
    float* ws  = (float*)d_ws;

    vq_prep<<<8, 64, 0, stream>>>(enc, ws);
    vq_main<<<NBLK, 256, 0, stream>>>(x, ws, out, ws + WS_PART);
    vq_fin<<<1, 256, 0, stream>>>(ws + WS_PART, out);
}

// Round 5
// 62.385 us; speedup vs baseline: 8.3017x; 1.2107x over previous
//
#include <hip/hip_runtime.h>
#include <stdint.h>

#define VQ_N   131072   // rows = 32*64*64
#define VQ_D   64
#define VQ_K   512
#define NKT    32       // 512/16 k-tiles
#define NBLK   1024     // 4 waves/block x 32 rows/wave = 128 rows/block

typedef __attribute__((ext_vector_type(8))) short  short8;   // 8 x bf16 bits
typedef __attribute__((ext_vector_type(4))) float  f32x4;

// ws float-offsets:
#define WS_HN    0        // 512 f:  32 + 0.5*||e_k||^2
#define WS_CBT   512      // 512*64 f: codebook, codeword-major cbt[k][d]
#define WS_FRAG  33280    // bf16x8 frag[32 kt][4 j][64 lane]; j: 0=eh d0,1=eh d1,2=el d0,3=el d1
#define WS_PART  66048    // NBLK f: per-block loss partials

__device__ __forceinline__ unsigned short f2bf(float f) {   // RNE f32->bf16 bits
    unsigned u = __float_as_uint(f);
    u += 0x7FFFu + ((u >> 16) & 1u);
    return (unsigned short)(u >> 16);
}
__device__ __forceinline__ float bf2f(unsigned short h) {
    return __uint_as_float(((unsigned)h) << 16);
}

// Build negated bf16 split of 8 floats: yh = bf16(-x), yl = bf16(-x - yh)
__device__ __forceinline__ void cvt8neg(float4 a, float4 b, short8& hi, short8& lo) {
    float f[8] = {a.x, a.y, a.z, a.w, b.x, b.y, b.z, b.w};
    union { short8 v; unsigned short u[8]; } H, L;
    #pragma unroll
    for (int e = 0; e < 8; ++e) {
        float y = -f[e];
        unsigned short h = f2bf(y);
        H.u[e] = h;
        L.u[e] = f2bf(y - bf2f(h));
    }
    hi = H.v; lo = L.v;
}

__device__ __forceinline__ bool lexlt(float s1, unsigned i1, float s2, unsigned i2) {
    return (s1 < s2) || ((s1 == s2) && (i1 < i2));
}

// ---------------- prep: codebook norms, fp32 transpose, bf16-split fragments ------
__global__ __launch_bounds__(64) void vq_prep(const float* __restrict__ enc,
                                              float* __restrict__ ws) {
    const int k  = blockIdx.x * 64 + threadIdx.x;   // 0..511
    const int kt = k >> 4, c = k & 15;
    float* cbt = ws + WS_CBT;
    unsigned short* frag = (unsigned short*)(ws + WS_FRAG);
    double hs = 0.0;
    for (int d = 0; d < VQ_D; ++d) {
        float v = enc[d * VQ_K + k];               // enc is [D][K]
        cbt[k * VQ_D + d] = v;
        hs += (double)v * (double)v;
        const int t = d >> 5, g = (d >> 3) & 3, e = d & 7;
        const int lane = 16 * g + c;
        unsigned short h = f2bf(v);
        frag[(((kt * 4) + t)     * 64 + lane) * 8 + e] = h;                 // eh
        frag[(((kt * 4) + 2 + t) * 64 + lane) * 8 + e] = f2bf(v - bf2f(h)); // el
    }
    ws[WS_HN + k] = 32.0f + 0.5f * (float)hs;
}

// ---------------- main: MFMA screen (cands-in-M) + top-2 + f64 rescreen -----------
__global__ __launch_bounds__(256) void vq_main(const float* __restrict__ x,
                                               const float* __restrict__ ws,
                                               float* __restrict__ out,
                                               float* __restrict__ partials) {
    const int tid = threadIdx.x;
    const int l   = tid & 63;          // lane
    const int wid = tid >> 6;          // wave in block
    const int m   = l & 15;            // x-row within set (C col), frag spatial idx
    const int g   = l >> 4;            // k-group (d-slice / cand-quad group)
    const int rowbase = (blockIdx.x * 4 + wid) * 32;

    const float*  __restrict__ hn   = ws + WS_HN;
    const float*  __restrict__ cbt  = ws + WS_CBT;
    const short8* __restrict__ frag = (const short8*)(ws + WS_FRAG);

    // Two 16-row sets per wave; x kept exactly in regs for rescreen/loss.
    float4 xa0[2], xa1[2], xb0[2], xb1[2];
    short8 yh0[2], yl0[2], yh1[2], yl1[2];
    #pragma unroll
    for (int s = 0; s < 2; ++s) {
        const float* xr = x + (size_t)(rowbase + s * 16 + m) * VQ_D;
        xa0[s] = *(const float4*)(xr + 8 * g);
        xa1[s] = *(const float4*)(xr + 8 * g + 4);
        xb0[s] = *(const float4*)(xr + 32 + 8 * g);
        xb1[s] = *(const float4*)(xr + 32 + 8 * g + 4);
        cvt8neg(xa0[s], xa1[s], yh0[s], yl0[s]);
        cvt8neg(xb0[s], xb1[s], yh1[s], yl1[s]);
    }

    float    b1s[2] = {3.4e38f, 3.4e38f}, b2s[2] = {3.4e38f, 3.4e38f};
    unsigned b1i[2] = {0, 0},             b2i[2] = {0, 0};

    for (int kt = 0; kt < NKT; ++kt) {
        short8 f0 = frag[(kt * 4 + 0) * 64 + l];   // eh d-half0
        short8 f1 = frag[(kt * 4 + 1) * 64 + l];   // eh d-half1
        short8 f2 = frag[(kt * 4 + 2) * 64 + l];   // el d-half0
        short8 f3 = frag[(kt * 4 + 3) * 64 + l];   // el d-half1
        float4 h4 = *(const float4*)(hn + kt * 16 + 4 * g);
        const unsigned base = (unsigned)(kt * 16 + 4 * g);

        #pragma unroll
        for (int s = 0; s < 2; ++s) {
            f32x4 acc = {h4.x, h4.y, h4.z, h4.w};
            acc = __builtin_amdgcn_mfma_f32_16x16x32_bf16(f0, yh0[s], acc, 0, 0, 0);
            acc = __builtin_amdgcn_mfma_f32_16x16x32_bf16(f1, yh1[s], acc, 0, 0, 0);
            acc = __builtin_amdgcn_mfma_f32_16x16x32_bf16(f2, yh0[s], acc, 0, 0, 0);
            acc = __builtin_amdgcn_mfma_f32_16x16x32_bf16(f3, yh1[s], acc, 0, 0, 0);
            acc = __builtin_amdgcn_mfma_f32_16x16x32_bf16(f0, yl0[s], acc, 0, 0, 0);
            acc = __builtin_amdgcn_mfma_f32_16x16x32_bf16(f1, yl1[s], acc, 0, 0, 0);
            // acc[r] = score of cand base+r for x-row rowbase+s*16+m

            // quad top-2 (idx pref: lower r on ties)
            float a0 = acc[0], a1 = acc[1], a2 = acc[2], a3 = acc[3];
            bool c01 = a1 < a0;
            float lo01 = c01 ? a1 : a0, hi01 = c01 ? a0 : a1;
            unsigned i01 = c01 ? 1u : 0u;
            bool c23 = a3 < a2;
            float lo23 = c23 ? a3 : a2, hi23 = c23 ? a2 : a3;
            unsigned i23 = c23 ? 3u : 2u;
            bool cb = lo23 < lo01;
            float    q1  = cb ? lo23 : lo01;
            unsigned q1i = cb ? i23  : i01;
            float    u   = cb ? lo01 : lo23;
            unsigned ui  = cb ? i01  : i23;
            float    v   = cb ? hi23 : hi01;
            unsigned vi  = cb ? (i23 ^ 1u) : (i01 ^ 1u);
            // tie -> lower idx: cb: idx(u)<idx(v) use v<u;  !cb: idx(v)<idx(u) use !(u<v)
            bool takeV = cb ? (v < u) : !(u < v);
            float    q2  = takeV ? v  : u;
            unsigned q2i = takeV ? vi : ui;
            q1i += base; q2i += base;

            // merge into running top-2 (all new idx > all old idx; ties keep old)
            bool t1 = q1 < b1s[s];
            float    nu  = t1 ? b1s[s] : b2s[s];
            unsigned nui = t1 ? b1i[s] : b2i[s];
            float    nv  = t1 ? q2  : q1;
            unsigned nvi = t1 ? q2i : q1i;
            b1s[s] = t1 ? q1  : b1s[s];
            b1i[s] = t1 ? q1i : b1i[s];
            bool w = nv < nu;
            b2s[s] = w ? nv  : nu;
            b2i[s] = w ? nvi : nui;
        }
    }

    // butterfly allreduce of top-2 across the 4 k-groups (lanes sharing col m)
    #pragma unroll
    for (int st = 16; st <= 32; st <<= 1) {
        #pragma unroll
        for (int s = 0; s < 2; ++s) {
            float    o1s = __shfl_xor(b1s[s], st, 64);
            unsigned o1i = (unsigned)__shfl_xor((int)b1i[s], st, 64);
            float    o2s = __shfl_xor(b2s[s], st, 64);
            unsigned o2i = (unsigned)__shfl_xor((int)b2i[s], st, 64);
            bool c = lexlt(o1s, o1i, b1s[s], b1i[s]);
            float    n1s = c ? o1s : b1s[s];
            unsigned n1i = c ? o1i : b1i[s];
            float    lss = c ? b1s[s] : o1s;     // loser of the firsts
            unsigned lsi = c ? b1i[s] : o1i;
            bool c2 = lexlt(b2s[s], b2i[s], o2s, o2i);
            float    m2s = c2 ? b2s[s] : o2s;
            unsigned m2i = c2 ? b2i[s] : o2i;
            bool c3 = lexlt(lss, lsi, m2s, m2i);
            b1s[s] = n1s; b1i[s] = n1i;
            b2s[s] = c3 ? lss : m2s;
            b2i[s] = c3 ? lsi : m2i;
        }
    }

    // rescreen + write + loss, per set
    float ls = 0.f;
    #pragma unroll
    for (int s = 0; s < 2; ++s) {
        const unsigned i1 = b1i[s], i2 = b2i[s];
        const float* e1p = cbt + (size_t)i1 * VQ_D;
        const float* e2p = cbt + (size_t)i2 * VQ_D;
        float4 p10 = *(const float4*)(e1p + 8 * g);
        float4 p11 = *(const float4*)(e1p + 8 * g + 4);
        float4 p12 = *(const float4*)(e1p + 32 + 8 * g);
        float4 p13 = *(const float4*)(e1p + 32 + 8 * g + 4);
        float4 p20 = *(const float4*)(e2p + 8 * g);
        float4 p21 = *(const float4*)(e2p + 8 * g + 4);
        float4 p22 = *(const float4*)(e2p + 32 + 8 * g);
        float4 p23 = *(const float4*)(e2p + 32 + 8 * g + 4);

        double dd1 = 0.0, dd2 = 0.0;
        {
            const float xs[16] = {xa0[s].x,xa0[s].y,xa0[s].z,xa0[s].w,
                                  xa1[s].x,xa1[s].y,xa1[s].z,xa1[s].w,
                                  xb0[s].x,xb0[s].y,xb0[s].z,xb0[s].w,
                                  xb1[s].x,xb1[s].y,xb1[s].z,xb1[s].w};
            const float q1v[16] = {p10.x,p10.y,p10.z,p10.w, p11.x,p11.y,p11.z,p11.w,
                                   p12.x,p12.y,p12.z,p12.w, p13.x,p13.y,p13.z,p13.w};
            const float q2v[16] = {p20.x,p20.y,p20.z,p20.w, p21.x,p21.y,p21.z,p21.w,
                                   p22.x,p22.y,p22.z,p22.w, p23.x,p23.y,p23.z,p23.w};
            #pragma unroll
            for (int j = 0; j < 16; ++j) {
                double u1 = (double)xs[j] - (double)q1v[j];
                double u2 = (double)xs[j] - (double)q2v[j];
                dd1 = fma(u1, u1, dd1);
                dd2 = fma(u2, u2, dd2);
            }
        }
        dd1 += __shfl_xor(dd1, 16, 64);  dd1 += __shfl_xor(dd1, 32, 64);
        dd2 += __shfl_xor(dd2, 16, 64);  dd2 += __shfl_xor(dd2, 32, 64);
        const bool take1 = (dd1 < dd2) || ((dd1 == dd2) && (i1 < i2));

        float4 q0, q1o, q2o, q3o;
        q0.x  = take1 ? p10.x : p20.x; q0.y  = take1 ? p10.y : p20.y;
        q0.z  = take1 ? p10.z : p20.z; q0.w  = take1 ? p10.w : p20.w;
        q1o.x = take1 ? p11.x : p21.x; q1o.y = take1 ? p11.y : p21.y;
        q1o.z = take1 ? p11.z : p21.z; q1o.w = take1 ? p11.w : p21.w;
        q2o.x = take1 ? p12.x : p22.x; q2o.y = take1 ? p12.y : p22.y;
        q2o.z = take1 ? p12.z : p22.z; q2o.w = take1 ? p12.w : p22.w;
        q3o.x = take1 ? p13.x : p23.x; q3o.y = take1 ? p13.y : p23.y;
        q3o.z = take1 ? p13.z : p23.z; q3o.w = take1 ? p13.w : p23.w;

        float* orow = out + (size_t)(rowbase + s * 16 + m) * VQ_D;
        *(float4*)(orow + 8 * g)          = q0;
        *(float4*)(orow + 8 * g + 4)      = q1o;
        *(float4*)(orow + 32 + 8 * g)     = q2o;
        *(float4*)(orow + 32 + 8 * g + 4) = q3o;

        float d;
        d = q0.x  - xa0[s].x; ls = fmaf(d, d, ls);  d = q0.y  - xa0[s].y; ls = fmaf(d, d, ls);
        d = q0.z  - xa0[s].z; ls = fmaf(d, d, ls);  d = q0.w  - xa0[s].w; ls = fmaf(d, d, ls);
        d = q1o.x - xa1[s].x; ls = fmaf(d, d, ls);  d = q1o.y - xa1[s].y; ls = fmaf(d, d, ls);
        d = q1o.z - xa1[s].z; ls = fmaf(d, d, ls);  d = q1o.w - xa1[s].w; ls = fmaf(d, d, ls);
        d = q2o.x - xb0[s].x; ls = fmaf(d, d, ls);  d = q2o.y - xb0[s].y; ls = fmaf(d, d, ls);
        d = q2o.z - xb0[s].z; ls = fmaf(d, d, ls);  d = q2o.w - xb0[s].w; ls = fmaf(d, d, ls);
        d = q3o.x - xb1[s].x; ls = fmaf(d, d, ls);  d = q3o.y - xb1[s].y; ls = fmaf(d, d, ls);
        d = q3o.z - xb1[s].z; ls = fmaf(d, d, ls);  d = q3o.w - xb1[s].w; ls = fmaf(d, d, ls);
    }

    #pragma unroll
    for (int off = 32; off > 0; off >>= 1) ls += __shfl_xor(ls, off, 64);

    __shared__ float lsw[4];
    if ((tid & 63) == 0) lsw[wid] = ls;
    __syncthreads();
    if (tid == 0) partials[blockIdx.x] = lsw[0] + lsw[1] + lsw[2] + lsw[3];
}

// ---------------- finalize: deterministic partial-sum + scale ---------------------
__global__ __launch_bounds__(256) void vq_fin(const float* __restrict__ partials,
                                              float* __restrict__ out) {
    const int tid = threadIdx.x;
    float s = 0.f;
    #pragma unroll
    for (int j = 0; j < NBLK / 256; ++j) s += partials[tid + 256 * j];
    #pragma unroll
    for (int off = 32; off > 0; off >>= 1) s += __shfl_xor(s, off, 64);
    __shared__ float w[4];
    if ((tid & 63) == 0) w[tid >> 6] = s;
    __syncthreads();
    if (tid == 0)
        out[(size_t)VQ_N * VQ_D] = 1.25f * (w[0] + w[1] + w[2] + w[3]) / 8388608.0f;
}

extern "C" void kernel_launch(void* const* d_in, const int* in_sizes, int n_in,
                              void* d_out, int out_size, void* d_ws, size_t ws_size,
                              hipStream_t stream) {
    const float* x   = (const float*)d_in[0];   // (32,64,64,64) fp32
    const float* enc = (const float*)d_in[1];   // (64,512) fp32
    float* out = (float*)d_out;                 // 8388608 quantised + 1 loss
    float* ws  = (float*)d_ws;

    vq_prep<<<8, 64, 0, stream>>>(enc, ws);
    vq_main<<<NBLK, 256, 0, stream>>>(x, ws, out, ws + WS_PART);
    vq_fin<<<1, 256, 0, stream>>>(ws + WS_PART, out);
}